// Round 1
// baseline (729.574 us; speedup 1.0000x reference)
//
#include <hip/hip_runtime.h>

// ParabolicPool2D: out[b,c,i,j] = max_{u,v} f[b,c, 2i+u-3, 2j+v-3] + h[u] + h[v]
// h separable under max-plus: h[u,v] = hu[u] + hu[v].
// f: (16,128,256,256) fp32; out: (16,128,128,128) fp32. Memory-bound (~640 MiB traffic).

#define KS 7
#define PAD 3
#define H 256
#define W 256
#define HO 128
#define WO 128
#define TH 32            // output tile rows per block
#define TW 32            // output tile cols per block
#define ROWS 69          // input rows needed: 2*TH+5
#define COLS 72          // input floats loaded per row (18 float4), covers needed 69 + align slack
#define SSTRIDE 76       // LDS input row stride (floats); 76 % 32 == 12 -> b128 reads hit all banks
#define GSTRIDE 36       // LDS g row stride (floats)

__global__ __launch_bounds__(256)
void pp_kernel(const float* __restrict__ f, const float* __restrict__ tptr,
               float* __restrict__ out) {
    __shared__ float sin_[ROWS * SSTRIDE];   // 20976 B
    __shared__ float g_[ROWS * GSTRIDE];     //  9936 B  (total 30.9 KB -> 5 blocks/CU)

    const int tid   = threadIdx.x;
    const int blk   = blockIdx.x;
    const int tile  = blk & 15;        // 16 tiles per (b,c) plane: 4x4
    const int plane = blk >> 4;        // b*128 + c
    const int i0 = (tile >> 2) * TH;   // output row origin
    const int j0 = (tile & 3) * TW;    // output col origin

    const float tv = tptr[0];
    float hu[KS];
#pragma unroll
    for (int v = 0; v < KS; ++v) {
        const float z = (float)(v - PAD);
        hu[v] = -(z * z) / (4.0f * tv);
    }

    // Input tile origin in global coords. x shifted to 2j0-4 (multiple of 4) so
    // every float4 is fully in-bounds or fully out-of-bounds in x.
    const int gy0 = 2 * i0 - 3;
    const int gx0 = 2 * j0 - 4;
    const float* fplane = f + (size_t)plane * (H * W);
    const float NEG = -__builtin_inff();

    // ---- Phase 1: global -> LDS, float4, coalesced ----
#pragma unroll 1
    for (int idx = tid; idx < ROWS * (COLS / 4); idx += 256) {
        const int r  = idx / (COLS / 4);
        const int c4 = idx - r * (COLS / 4);
        const int gy = gy0 + r;
        const int gx = gx0 + 4 * c4;
        float4 val;
        if (gy >= 0 && gy < H && gx >= 0 && gx < W) {
            val = *(const float4*)(fplane + gy * W + gx);
        } else {
            val = make_float4(NEG, NEG, NEG, NEG);
        }
        *(float4*)(&sin_[r * SSTRIDE + 4 * c4]) = val;
    }
    __syncthreads();

    // ---- Phase 2: horizontal max-plus: g[y][j] = max_v sin[y][2j+1+v] + hu[v] ----
    // (local x=0 is global 2j0-4, so window for output col j is local [2j+1, 2j+7])
    {
        const int q  = tid & 7;        // which run of 4 g-columns
        const int yb = tid >> 3;       // row base, 0..31
        const int jr = q * 4;
#pragma unroll 1
        for (int y = yb; y < ROWS; y += 32) {
            const float* row = &sin_[y * SSTRIDE + 2 * jr];   // 16B-aligned
            const float4 w0 = *(const float4*)(row);
            const float4 w1 = *(const float4*)(row + 4);
            const float4 w2 = *(const float4*)(row + 8);
            const float4 w3 = *(const float4*)(row + 12);
            const float s[16] = {w0.x, w0.y, w0.z, w0.w, w1.x, w1.y, w1.z, w1.w,
                                 w2.x, w2.y, w2.z, w2.w, w3.x, w3.y, w3.z, w3.w};
            float4 gv;
            float* gp = (float*)&gv;
#pragma unroll
            for (int jj = 0; jj < 4; ++jj) {
                float m = s[2 * jj + 1] + hu[0];
#pragma unroll
                for (int v = 1; v < KS; ++v)
                    m = fmaxf(m, s[2 * jj + 1 + v] + hu[v]);
                gp[jj] = m;
            }
            *(float4*)(&g_[y * GSTRIDE + jr]) = gv;
        }
    }
    __syncthreads();

    // ---- Phase 3: vertical max-plus + coalesced store ----
    {
        const int j  = tid & 31;
        const int ir = (tid >> 5) * 4;      // 0,4,...,28
        float col[13];
#pragma unroll
        for (int k = 0; k < 13; ++k)
            col[k] = g_[(2 * ir + k) * GSTRIDE + j];
        float* oplane = out + (size_t)plane * (HO * WO);
#pragma unroll
        for (int ii = 0; ii < 4; ++ii) {
            float m = col[2 * ii] + hu[0];
#pragma unroll
            for (int u = 1; u < KS; ++u)
                m = fmaxf(m, col[2 * ii + u] + hu[u]);
            oplane[(size_t)(i0 + ir + ii) * WO + (j0 + j)] = m;
        }
    }
}

extern "C" void kernel_launch(void* const* d_in, const int* in_sizes, int n_in,
                              void* d_out, int out_size, void* d_ws, size_t ws_size,
                              hipStream_t stream) {
    const float* f = (const float*)d_in[0];
    const float* t = (const float*)d_in[1];
    float* out = (float*)d_out;
    // 2048 planes (16*128) x 16 tiles each
    pp_kernel<<<dim3(2048 * 16), dim3(256), 0, stream>>>(f, t, out);
}